// Round 10
// baseline (662.519 us; speedup 1.0000x reference)
//
#include <hip/hip_runtime.h>
#include <hip/hip_bf16.h>
#include <math.h>

// ---------------------------------------------------------------------------
// YatNMN: out = scale * ( y^2/(||x||^2+||w||^2-2y+eps) + bias ), y = x@W
// x:[16384,2048] f32, W:[2048,8192] f32, out f32 [16384,8192].
// R10: 2 blocks/CU to break the read||MFMA lockstep serialization.
// 256x128 block, 8 waves x 64x64, BK=32, triple-buffered LDS 72KB/block,
// counted vmcnt(3), 2 barriers/tile, BK=32 slot-swizzle (kh ^ (row&3)),
// XCD band swizzle. NT loads in prologues; plain output stores (R9's NT
// stores hurt: WRITE 524->700MB, refuted).
// Workspace: [0) xbf 64MB | [64M) ktb 32MB | xs | ks | kpart (<=2MB)
// ---------------------------------------------------------------------------

#define EPS_F (1.0f / 137.0f)
#define M_DIM 16384
#define N_DIM 8192
#define K_DIM 2048

typedef __attribute__((ext_vector_type(8))) short short8;
typedef __attribute__((ext_vector_type(4))) float f32x4;

__device__ __forceinline__ unsigned short f2bf(float f) {
  unsigned int u = __float_as_uint(f);
  u += 0x7fffu + ((u >> 16) & 1u);
  return (unsigned short)(u >> 16);
}

typedef __attribute__((address_space(1))) const unsigned int as1_cuint;
typedef __attribute__((address_space(3))) unsigned int as3_uint;

__device__ __forceinline__ void gload16(const void* g, void* lds_wave_base) {
  __builtin_amdgcn_global_load_lds((as1_cuint*)g, (as3_uint*)lds_wave_base, 16, 0, 0);
}

// --------------------------- prologue kernels ------------------------------

__global__ __launch_bounds__(256) void k_conv_x(const float* __restrict__ x,
                                                unsigned short* __restrict__ xbf,
                                                float* __restrict__ xs) {
  const int row = blockIdx.x;
  const int t = threadIdx.x;
  const f32x4* xr = (const f32x4*)(x + (size_t)row * K_DIM);
  ushort4* orow = (ushort4*)(xbf + (size_t)row * K_DIM);
  float s = 0.f;
#pragma unroll
  for (int i = 0; i < 2; ++i) {
    f32x4 v = __builtin_nontemporal_load(&xr[t + i * 256]);  // read-once
    s += v.x * v.x + v.y * v.y + v.z * v.z + v.w * v.w;
    ushort4 o;
    o.x = f2bf(v.x); o.y = f2bf(v.y); o.z = f2bf(v.z); o.w = f2bf(v.w);
    orow[t + i * 256] = o;  // cached: GEMM reads this soon
  }
#pragma unroll
  for (int off = 32; off > 0; off >>= 1) s += __shfl_down(s, off, 64);
  __shared__ float red[4];
  if ((t & 63) == 0) red[t >> 6] = s;
  __syncthreads();
  if (t == 0) xs[row] = red[0] + red[1] + red[2] + red[3];
}

// W [K][N] f32 -> W^T [N][K] bf16, fused per-(32-row-block, col) ssq partials.
__global__ __launch_bounds__(256) void k_conv_kT_fused(const float* __restrict__ w,
                                                       unsigned short* __restrict__ bt,
                                                       float* __restrict__ kpart) {
  __shared__ float tile[32][33];
  __shared__ float psum[8][33];
  const int tx = threadIdx.x;
  const int ty = threadIdx.y;
  const int n0 = blockIdx.x * 32;
  const int k0 = blockIdx.y * 32;
  float ss = 0.f;
#pragma unroll
  for (int j = 0; j < 32; j += 8) {
    float v = __builtin_nontemporal_load(&w[(size_t)(k0 + ty + j) * N_DIM + n0 + tx]);
    tile[ty + j][tx] = v;
    ss += v * v;
  }
  psum[ty][tx] = ss;
  __syncthreads();
#pragma unroll
  for (int j = 0; j < 32; j += 8)
    bt[(size_t)(n0 + ty + j) * K_DIM + k0 + tx] = f2bf(tile[tx][ty + j]);
  if (ty == 0) {
    float s = 0.f;
#pragma unroll
    for (int r = 0; r < 8; ++r) s += psum[r][tx];
    kpart[(size_t)(k0 >> 5) * N_DIM + n0 + tx] = s;
  }
}

__global__ __launch_bounds__(256) void k_conv_kT(const float* __restrict__ w,
                                                 unsigned short* __restrict__ bt) {
  __shared__ float tile[32][33];
  const int tx = threadIdx.x;
  const int ty = threadIdx.y;
  const int n0 = blockIdx.x * 32;
  const int k0 = blockIdx.y * 32;
#pragma unroll
  for (int j = 0; j < 32; j += 8)
    tile[ty + j][tx] = __builtin_nontemporal_load(&w[(size_t)(k0 + ty + j) * N_DIM + n0 + tx]);
  __syncthreads();
#pragma unroll
  for (int j = 0; j < 32; j += 8)
    bt[(size_t)(n0 + ty + j) * K_DIM + k0 + tx] = f2bf(tile[tx][ty + j]);
}

__global__ __launch_bounds__(256) void k_ksq_part(const float* __restrict__ w,
                                                  float* __restrict__ kpart) {
  const int col = blockIdx.x * 256 + threadIdx.x;
  const int kb = blockIdx.y;
  float s = 0.f;
#pragma unroll 4
  for (int k = kb * 128; k < kb * 128 + 128; ++k) {
    float v = w[(size_t)k * N_DIM + col];
    s += v * v;
  }
  kpart[kb * N_DIM + col] = s;
}

__global__ __launch_bounds__(256) void k_ksq_fin(const float* __restrict__ kpart,
                                                 float* __restrict__ ks, int nkb) {
  const int col = blockIdx.x * 256 + threadIdx.x;
  float s = 0.f;
  for (int kb = 0; kb < nkb; ++kb) s += kpart[(size_t)kb * N_DIM + col];
  ks[col] = s;
}

// ------------------------------- GEMM 256x128, BK=32, 2 blocks/CU ----------
// A: xbf [M][K] bf16.  B: ktb [N][K] bf16.
// 8 waves: wr=wid>>1 (4 M-bands of 64), wc=wid&1 (2 N-halves of 64).
// acc[4][4] f32x4 = 64 VGPR; frags a[4]+b[4] = 32 -> ~115 total <= 128.
// LDS per block: sA 3x16KB + sB 3x8KB = 72KB -> two blocks co-resident.
// Tile rows are 64B (32 bf16); swizzle: 16B-slot' = kh ^ (row&3) on reads,
// inverse pre-applied to the gload_lds global source (LDS written linearly).
// Per K-tile tau (cur buf tau%3): stage tile tau+2 (3 calls) into buf
// (tau+2)%3, 8 ds_reads of tau's frags, vmcnt(3) (tau+1 landed; tau+2's 3
// in flight), barrier, lgkmcnt(0)+sched_barrier, 16 MFMA, barrier.
// Overlap comes from the second, unsynchronized block on the same CU.

#define MFMA_OP(d, va, vb) \
  d = __builtin_amdgcn_mfma_f32_16x16x32_bf16(va, vb, d, 0, 0, 0)

#define BARRIER __builtin_amdgcn_s_barrier()
#define LGKM0_SGB do { \
  asm volatile("s_waitcnt lgkmcnt(0)" ::: "memory"); \
  __builtin_amdgcn_sched_barrier(0); \
} while (0)
#define VMCNT3 asm volatile("s_waitcnt vmcnt(3)" ::: "memory")

__global__ __launch_bounds__(512, 4) void k_gemm(const unsigned short* __restrict__ A,
                                                 const unsigned short* __restrict__ B,
                                                 const float* __restrict__ xs,
                                                 const float* __restrict__ ks,
                                                 const float* __restrict__ bias,
                                                 const float* __restrict__ alpha,
                                                 float* __restrict__ out) {
  __shared__ __align__(16) char lds[73728];
  char* sA = lds;           // 3 x 16384
  char* sB = lds + 49152;   // 3 x 8192

  const int t = threadIdx.x;
  const int lane = t & 63;
  const int wid = t >> 6;
  const int wr = wid >> 1;  // 0..3 (M band of 64)
  const int wc = wid & 1;   // 0..1 (N half of 64)
  const int lr = lane & 15;
  const int kh = lane >> 4;           // 0..3 (16B k-granule)
  const int rdslot = (kh ^ (lr & 3)) << 4;  // swizzled byte slot for reads

  // XCD band swizzle (bijective: 4096 = 8 xcd * 8 chunks * 64).
  // XCD owns tm band [8*xcd, 8*xcd+8) x all tn; walked in 8tm x 8tn chunks.
  const int bid = blockIdx.x;
  const int xcd = bid & 7;
  const int sub = bid >> 3;    // 0..511
  const int ch  = sub >> 6;    // 0..7
  const int w64 = sub & 63;
  const int tm = xcd * 8 + (w64 >> 3);   // 0..63
  const int tn = ch * 8 + (w64 & 7);     // 0..63
  const size_t rowM0 = (size_t)tm * 256;
  const size_t colN0 = (size_t)tn * 128;

  // staging: one gload16 covers 16 rows x 64B (1KB). lane l -> physical
  // (row_p = l>>2, slot_p = l&3); logical k-granule = slot_p ^ (row_p&3).
  const int row_p = lane >> 2;
  const int slot_p = lane & 3;
  const int kg = slot_p ^ (row_p & 3);
  const unsigned short* gA0 = A + (rowM0 + wid * 16 + row_p) * K_DIM + kg * 8;
  const unsigned short* gB0 = B + (colN0 + wid * 16 + row_p) * K_DIM + kg * 8;

// stage A half s (rows [128s + wid*16, +16)) / B (rows [wid*16, +16)) of the
// tile at k-elem offset ko into byte-offset buf
#define STAGE_A(boff, s, ko) \
  gload16(gA0 + (size_t)(s) * 128 * K_DIM + (ko), \
          sA + (boff) + ((s) * 128 + wid * 16) * 64)
#define STAGE_B(boff, ko) \
  gload16(gB0 + (ko), sB + (boff) + wid * 16 * 64)

#define RD_A(boff, m) \
  (*(const short8*)(sA + (boff) + (wr * 64 + (m) * 16 + lr) * 64 + rdslot))
#define RD_B(boff, n) \
  (*(const short8*)(sB + (boff) + (wc * 64 + (n) * 16 + lr) * 64 + rdslot))

  f32x4 acc[4][4] = {};
  short8 a[4], b[4];

#define MFMA16() do { \
  __builtin_amdgcn_s_setprio(1); \
  MFMA_OP(acc[0][0], a[0], b[0]); MFMA_OP(acc[0][1], a[0], b[1]); \
  MFMA_OP(acc[0][2], a[0], b[2]); MFMA_OP(acc[0][3], a[0], b[3]); \
  MFMA_OP(acc[1][0], a[1], b[0]); MFMA_OP(acc[1][1], a[1], b[1]); \
  MFMA_OP(acc[1][2], a[1], b[2]); MFMA_OP(acc[1][3], a[1], b[3]); \
  MFMA_OP(acc[2][0], a[2], b[0]); MFMA_OP(acc[2][1], a[2], b[1]); \
  MFMA_OP(acc[2][2], a[2], b[2]); MFMA_OP(acc[2][3], a[2], b[3]); \
  MFMA_OP(acc[3][0], a[3], b[0]); MFMA_OP(acc[3][1], a[3], b[1]); \
  MFMA_OP(acc[3][2], a[3], b[2]); MFMA_OP(acc[3][3], a[3], b[3]); \
  __builtin_amdgcn_s_setprio(0); \
} while (0)

// one K-tile: cur bufs (cbA,cbB), stage target bufs (sbA,sbB), stage k-off ko
#define TILE32(cbA, cbB, sbA, sbB, ko) do { \
  STAGE_A(sbA, 0, ko); STAGE_A(sbA, 1, ko); STAGE_B(sbB, ko); \
  a[0] = RD_A(cbA, 0); a[1] = RD_A(cbA, 1); \
  a[2] = RD_A(cbA, 2); a[3] = RD_A(cbA, 3); \
  b[0] = RD_B(cbB, 0); b[1] = RD_B(cbB, 1); \
  b[2] = RD_B(cbB, 2); b[3] = RD_B(cbB, 3); \
  VMCNT3; BARRIER; LGKM0_SGB; \
  MFMA16(); \
  BARRIER; \
} while (0)

  // prologue: stage tile0 -> buf0, tile1 -> buf1
  STAGE_A(0, 0, 0); STAGE_A(0, 1, 0); STAGE_B(0, 0);
  STAGE_A(16384, 0, 32); STAGE_A(16384, 1, 32); STAGE_B(8192, 32);
  VMCNT3;  // tile0 landed; tile1's 3 in flight
  BARRIER;

#pragma unroll 1
  for (int i = 0; i < 21; ++i) {
    const int t0 = 3 * i;
    const int ko0 = (t0 + 2) * 32;                        // <= 62*32, real
    const int ko1 = (t0 + 3 < 64) ? (t0 + 3) * 32 : 0;    // clamp
    const int ko2 = (t0 + 4 < 64) ? (t0 + 4) * 32 : 0;    // clamp
    TILE32(0,     0,     32768, 16384, ko0);  // tau%3==0: cur 0, stage -> 2
    TILE32(16384, 8192,  0,     0,     ko1);  // tau%3==1: cur 1, stage -> 0
    TILE32(32768, 16384, 16384, 8192,  ko2);  // tau%3==2: cur 2, stage -> 1
  }
  // final tile 63 (buf 0); garbage stage -> buf 2, clamped
  TILE32(0, 0, 32768, 16384, 0);

  asm volatile("s_waitcnt vmcnt(0)" ::: "memory");

  // fused Yat epilogue. C/D: col = lane&15 (N), row = (lane>>4)*4 + reg (M).
  const float scale = powf(sqrtf(8192.0f) / log1pf(8192.0f), alpha[0]);
#pragma unroll
  for (int m = 0; m < 4; ++m) {
#pragma unroll
    for (int r = 0; r < 4; ++r) {
      const size_t grow = rowM0 + wr * 64 + m * 16 + kh * 4 + r;
      const float xq = xs[grow];
      float* orow = out + grow * N_DIM;
#pragma unroll
      for (int n = 0; n < 4; ++n) {
        const int gcol = (int)colN0 + wc * 64 + n * 16 + lr;
        const float y = acc[m][n][r];
        const float d = xq + ks[gcol] - 2.0f * y + EPS_F;
        const float v = y * y * __builtin_amdgcn_rcpf(d);
        orow[gcol] = (v + bias[gcol]) * scale;
      }
    }
  }
}

// ------------------------------ launch -------------------------------------

extern "C" void kernel_launch(void* const* d_in, const int* in_sizes, int n_in,
                              void* d_out, int out_size, void* d_ws, size_t ws_size,
                              hipStream_t stream) {
  const float* x     = (const float*)d_in[0];
  const float* w     = (const float*)d_in[1];
  const float* bias  = (const float*)d_in[2];
  const float* alpha = (const float*)d_in[3];
  float* out = (float*)d_out;
  char* ws = (char*)d_ws;

  unsigned short* xbf = (unsigned short*)(ws);
  unsigned short* ktb = (unsigned short*)(ws + 67108864);
  float* xs    = (float*)(ws + 100663296);
  float* ks    = (float*)(ws + 100728832);
  float* kpart = (float*)(ws + 100761600);

  k_conv_x<<<M_DIM, 256, 0, stream>>>(x, xbf, xs);
  if (ws_size >= 100761600ull + (size_t)64 * N_DIM * 4) {
    k_conv_kT_fused<<<dim3(N_DIM / 32, K_DIM / 32), dim3(32, 8), 0, stream>>>(w, ktb, kpart);
    k_ksq_fin<<<N_DIM / 256, 256, 0, stream>>>(kpart, ks, 64);
  } else {
    k_conv_kT<<<dim3(N_DIM / 32, K_DIM / 32), dim3(32, 8), 0, stream>>>(w, ktb);
    k_ksq_part<<<dim3(N_DIM / 256, 16), 256, 0, stream>>>(w, kpart);
    k_ksq_fin<<<N_DIM / 256, 256, 0, stream>>>(kpart, ks, 16);
  }
  k_gemm<<<(M_DIM / 256) * (N_DIM / 128), 512, 0, stream>>>(xbf, ktb, xs, ks, bias, alpha, out);
}

// Round 11
// 662.403 us; speedup vs baseline: 1.0002x; 1.0002x over previous
//
#include <hip/hip_runtime.h>
#include <hip/hip_bf16.h>
#include <math.h>

// ---------------------------------------------------------------------------
// YatNMN: out = scale * ( y^2/(||x||^2+||w||^2-2y+eps) + bias ), y = x@W
// x:[16384,2048] f32, W:[2048,8192] f32, out f32 [16384,8192].
// R11 = R10 with the corrected BK=32 LDS swizzle:
//   read slot' = kh ^ ((lr>>1)&3)   (was kh ^ (lr&3): 2-way conflicts, 6.7e7)
//   stage source granule kg = (l&3) ^ ((l>>3)&3)
// Every consecutive 8-lane group of a ds_read_b128 now covers all 8 16B
// granule classes of the 128B bank stripe -> conflict-free.
// 256x128 block, 8 waves x 64x64, BK=32, 3-buf LDS 72KB, 2 blocks/CU.
// Workspace: [0) xbf 64MB | [64M) ktb 32MB | xs | ks | kpart (<=2MB)
// ---------------------------------------------------------------------------

#define EPS_F (1.0f / 137.0f)
#define M_DIM 16384
#define N_DIM 8192
#define K_DIM 2048

typedef __attribute__((ext_vector_type(8))) short short8;
typedef __attribute__((ext_vector_type(4))) float f32x4;

__device__ __forceinline__ unsigned short f2bf(float f) {
  unsigned int u = __float_as_uint(f);
  u += 0x7fffu + ((u >> 16) & 1u);
  return (unsigned short)(u >> 16);
}

typedef __attribute__((address_space(1))) const unsigned int as1_cuint;
typedef __attribute__((address_space(3))) unsigned int as3_uint;

__device__ __forceinline__ void gload16(const void* g, void* lds_wave_base) {
  __builtin_amdgcn_global_load_lds((as1_cuint*)g, (as3_uint*)lds_wave_base, 16, 0, 0);
}

// --------------------------- prologue kernels ------------------------------

__global__ __launch_bounds__(256) void k_conv_x(const float* __restrict__ x,
                                                unsigned short* __restrict__ xbf,
                                                float* __restrict__ xs) {
  const int row = blockIdx.x;
  const int t = threadIdx.x;
  const f32x4* xr = (const f32x4*)(x + (size_t)row * K_DIM);
  ushort4* orow = (ushort4*)(xbf + (size_t)row * K_DIM);
  float s = 0.f;
#pragma unroll
  for (int i = 0; i < 2; ++i) {
    f32x4 v = __builtin_nontemporal_load(&xr[t + i * 256]);  // read-once
    s += v.x * v.x + v.y * v.y + v.z * v.z + v.w * v.w;
    ushort4 o;
    o.x = f2bf(v.x); o.y = f2bf(v.y); o.z = f2bf(v.z); o.w = f2bf(v.w);
    orow[t + i * 256] = o;  // cached: GEMM reads this soon
  }
#pragma unroll
  for (int off = 32; off > 0; off >>= 1) s += __shfl_down(s, off, 64);
  __shared__ float red[4];
  if ((t & 63) == 0) red[t >> 6] = s;
  __syncthreads();
  if (t == 0) xs[row] = red[0] + red[1] + red[2] + red[3];
}

// W [K][N] f32 -> W^T [N][K] bf16, fused per-(32-row-block, col) ssq partials.
__global__ __launch_bounds__(256) void k_conv_kT_fused(const float* __restrict__ w,
                                                       unsigned short* __restrict__ bt,
                                                       float* __restrict__ kpart) {
  __shared__ float tile[32][33];
  __shared__ float psum[8][33];
  const int tx = threadIdx.x;
  const int ty = threadIdx.y;
  const int n0 = blockIdx.x * 32;
  const int k0 = blockIdx.y * 32;
  float ss = 0.f;
#pragma unroll
  for (int j = 0; j < 32; j += 8) {
    float v = __builtin_nontemporal_load(&w[(size_t)(k0 + ty + j) * N_DIM + n0 + tx]);
    tile[ty + j][tx] = v;
    ss += v * v;
  }
  psum[ty][tx] = ss;
  __syncthreads();
#pragma unroll
  for (int j = 0; j < 32; j += 8)
    bt[(size_t)(n0 + ty + j) * K_DIM + k0 + tx] = f2bf(tile[tx][ty + j]);
  if (ty == 0) {
    float s = 0.f;
#pragma unroll
    for (int r = 0; r < 8; ++r) s += psum[r][tx];
    kpart[(size_t)(k0 >> 5) * N_DIM + n0 + tx] = s;
  }
}

__global__ __launch_bounds__(256) void k_conv_kT(const float* __restrict__ w,
                                                 unsigned short* __restrict__ bt) {
  __shared__ float tile[32][33];
  const int tx = threadIdx.x;
  const int ty = threadIdx.y;
  const int n0 = blockIdx.x * 32;
  const int k0 = blockIdx.y * 32;
#pragma unroll
  for (int j = 0; j < 32; j += 8)
    tile[ty + j][tx] = __builtin_nontemporal_load(&w[(size_t)(k0 + ty + j) * N_DIM + n0 + tx]);
  __syncthreads();
#pragma unroll
  for (int j = 0; j < 32; j += 8)
    bt[(size_t)(n0 + ty + j) * K_DIM + k0 + tx] = f2bf(tile[tx][ty + j]);
}

__global__ __launch_bounds__(256) void k_ksq_part(const float* __restrict__ w,
                                                  float* __restrict__ kpart) {
  const int col = blockIdx.x * 256 + threadIdx.x;
  const int kb = blockIdx.y;
  float s = 0.f;
#pragma unroll 4
  for (int k = kb * 128; k < kb * 128 + 128; ++k) {
    float v = w[(size_t)k * N_DIM + col];
    s += v * v;
  }
  kpart[kb * N_DIM + col] = s;
}

__global__ __launch_bounds__(256) void k_ksq_fin(const float* __restrict__ kpart,
                                                 float* __restrict__ ks, int nkb) {
  const int col = blockIdx.x * 256 + threadIdx.x;
  float s = 0.f;
  for (int kb = 0; kb < nkb; ++kb) s += kpart[(size_t)kb * N_DIM + col];
  ks[col] = s;
}

// ------------------------------- GEMM 256x128, BK=32, 2 blocks/CU ----------
// See R10 header. Swizzle (corrected):
//   physical slot s of row r holds k-granule  s ^ ((r>>1)&3)
//   read:  slot' = kh ^ ((lr>>1)&3)  (row parity supplies class bit2)
//   stage: lane l fetches granule (l&3) ^ ((l>>3)&3) of its chunk row l>>2
// Per-8-lane-group granule classes form a full permutation of 0..7 ->
// conflict-free ds_read_b128.

#define MFMA_OP(d, va, vb) \
  d = __builtin_amdgcn_mfma_f32_16x16x32_bf16(va, vb, d, 0, 0, 0)

#define BARRIER __builtin_amdgcn_s_barrier()
#define LGKM0_SGB do { \
  asm volatile("s_waitcnt lgkmcnt(0)" ::: "memory"); \
  __builtin_amdgcn_sched_barrier(0); \
} while (0)
#define VMCNT3 asm volatile("s_waitcnt vmcnt(3)" ::: "memory")

__global__ __launch_bounds__(512, 4) void k_gemm(const unsigned short* __restrict__ A,
                                                 const unsigned short* __restrict__ B,
                                                 const float* __restrict__ xs,
                                                 const float* __restrict__ ks,
                                                 const float* __restrict__ bias,
                                                 const float* __restrict__ alpha,
                                                 float* __restrict__ out) {
  __shared__ __align__(16) char lds[73728];
  char* sA = lds;           // 3 x 16384
  char* sB = lds + 49152;   // 3 x 8192

  const int t = threadIdx.x;
  const int lane = t & 63;
  const int wid = t >> 6;
  const int wr = wid >> 1;  // 0..3 (M band of 64)
  const int wc = wid & 1;   // 0..1 (N half of 64)
  const int lr = lane & 15;
  const int kh = lane >> 4;                       // 0..3 (16B k-granule)
  const int rdslot = (kh ^ ((lr >> 1) & 3)) << 4; // corrected swizzled slot

  // XCD band swizzle (bijective: 4096 = 8 xcd * 8 chunks * 64).
  const int bid = blockIdx.x;
  const int xcd = bid & 7;
  const int sub = bid >> 3;    // 0..511
  const int ch  = sub >> 6;    // 0..7
  const int w64 = sub & 63;
  const int tm = xcd * 8 + (w64 >> 3);   // 0..63
  const int tn = ch * 8 + (w64 & 7);     // 0..63
  const size_t rowM0 = (size_t)tm * 256;
  const size_t colN0 = (size_t)tn * 128;

  // staging: one gload16 covers 16 rows x 64B (1KB). lane l -> physical
  // (row_p = l>>2, slot_p = l&3); logical k-granule = (l&3) ^ ((l>>3)&3).
  const int row_p = lane >> 2;
  const int slot_p = lane & 3;
  const int kg = slot_p ^ ((lane >> 3) & 3);
  const unsigned short* gA0 = A + (rowM0 + wid * 16 + row_p) * K_DIM + kg * 8;
  const unsigned short* gB0 = B + (colN0 + wid * 16 + row_p) * K_DIM + kg * 8;

#define STAGE_A(boff, s, ko) \
  gload16(gA0 + (size_t)(s) * 128 * K_DIM + (ko), \
          sA + (boff) + ((s) * 128 + wid * 16) * 64)
#define STAGE_B(boff, ko) \
  gload16(gB0 + (ko), sB + (boff) + wid * 16 * 64)

#define RD_A(boff, m) \
  (*(const short8*)(sA + (boff) + (wr * 64 + (m) * 16 + lr) * 64 + rdslot))
#define RD_B(boff, n) \
  (*(const short8*)(sB + (boff) + (wc * 64 + (n) * 16 + lr) * 64 + rdslot))

  f32x4 acc[4][4] = {};
  short8 a[4], b[4];

#define MFMA16() do { \
  __builtin_amdgcn_s_setprio(1); \
  MFMA_OP(acc[0][0], a[0], b[0]); MFMA_OP(acc[0][1], a[0], b[1]); \
  MFMA_OP(acc[0][2], a[0], b[2]); MFMA_OP(acc[0][3], a[0], b[3]); \
  MFMA_OP(acc[1][0], a[1], b[0]); MFMA_OP(acc[1][1], a[1], b[1]); \
  MFMA_OP(acc[1][2], a[1], b[2]); MFMA_OP(acc[1][3], a[1], b[3]); \
  MFMA_OP(acc[2][0], a[2], b[0]); MFMA_OP(acc[2][1], a[2], b[1]); \
  MFMA_OP(acc[2][2], a[2], b[2]); MFMA_OP(acc[2][3], a[2], b[3]); \
  MFMA_OP(acc[3][0], a[3], b[0]); MFMA_OP(acc[3][1], a[3], b[1]); \
  MFMA_OP(acc[3][2], a[3], b[2]); MFMA_OP(acc[3][3], a[3], b[3]); \
  __builtin_amdgcn_s_setprio(0); \
} while (0)

#define TILE32(cbA, cbB, sbA, sbB, ko) do { \
  STAGE_A(sbA, 0, ko); STAGE_A(sbA, 1, ko); STAGE_B(sbB, ko); \
  a[0] = RD_A(cbA, 0); a[1] = RD_A(cbA, 1); \
  a[2] = RD_A(cbA, 2); a[3] = RD_A(cbA, 3); \
  b[0] = RD_B(cbB, 0); b[1] = RD_B(cbB, 1); \
  b[2] = RD_B(cbB, 2); b[3] = RD_B(cbB, 3); \
  VMCNT3; BARRIER; LGKM0_SGB; \
  MFMA16(); \
  BARRIER; \
} while (0)

  // prologue: stage tile0 -> buf0, tile1 -> buf1
  STAGE_A(0, 0, 0); STAGE_A(0, 1, 0); STAGE_B(0, 0);
  STAGE_A(16384, 0, 32); STAGE_A(16384, 1, 32); STAGE_B(8192, 32);
  VMCNT3;  // tile0 landed; tile1's 3 in flight
  BARRIER;

#pragma unroll 1
  for (int i = 0; i < 21; ++i) {
    const int t0 = 3 * i;
    const int ko0 = (t0 + 2) * 32;                        // <= 62*32, real
    const int ko1 = (t0 + 3 < 64) ? (t0 + 3) * 32 : 0;    // clamp
    const int ko2 = (t0 + 4 < 64) ? (t0 + 4) * 32 : 0;    // clamp
    TILE32(0,     0,     32768, 16384, ko0);  // tau%3==0: cur 0, stage -> 2
    TILE32(16384, 8192,  0,     0,     ko1);  // tau%3==1: cur 1, stage -> 0
    TILE32(32768, 16384, 16384, 8192,  ko2);  // tau%3==2: cur 2, stage -> 1
  }
  // final tile 63 (buf 0); garbage stage -> buf 2, clamped
  TILE32(0, 0, 32768, 16384, 0);

  asm volatile("s_waitcnt vmcnt(0)" ::: "memory");

  // fused Yat epilogue. C/D: col = lane&15 (N), row = (lane>>4)*4 + reg (M).
  const float scale = powf(sqrtf(8192.0f) / log1pf(8192.0f), alpha[0]);
#pragma unroll
  for (int m = 0; m < 4; ++m) {
#pragma unroll
    for (int r = 0; r < 4; ++r) {
      const size_t grow = rowM0 + wr * 64 + m * 16 + kh * 4 + r;
      const float xq = xs[grow];
      float* orow = out + grow * N_DIM;
#pragma unroll
      for (int n = 0; n < 4; ++n) {
        const int gcol = (int)colN0 + wc * 64 + n * 16 + lr;
        const float y = acc[m][n][r];
        const float d = xq + ks[gcol] - 2.0f * y + EPS_F;
        const float v = y * y * __builtin_amdgcn_rcpf(d);
        orow[gcol] = (v + bias[gcol]) * scale;
      }
    }
  }
}

// ------------------------------ launch -------------------------------------

extern "C" void kernel_launch(void* const* d_in, const int* in_sizes, int n_in,
                              void* d_out, int out_size, void* d_ws, size_t ws_size,
                              hipStream_t stream) {
  const float* x     = (const float*)d_in[0];
  const float* w     = (const float*)d_in[1];
  const float* bias  = (const float*)d_in[2];
  const float* alpha = (const float*)d_in[3];
  float* out = (float*)d_out;
  char* ws = (char*)d_ws;

  unsigned short* xbf = (unsigned short*)(ws);
  unsigned short* ktb = (unsigned short*)(ws + 67108864);
  float* xs    = (float*)(ws + 100663296);
  float* ks    = (float*)(ws + 100728832);
  float* kpart = (float*)(ws + 100761600);

  k_conv_x<<<M_DIM, 256, 0, stream>>>(x, xbf, xs);
  if (ws_size >= 100761600ull + (size_t)64 * N_DIM * 4) {
    k_conv_kT_fused<<<dim3(N_DIM / 32, K_DIM / 32), dim3(32, 8), 0, stream>>>(w, ktb, kpart);
    k_ksq_fin<<<N_DIM / 256, 256, 0, stream>>>(kpart, ks, 64);
  } else {
    k_conv_kT<<<dim3(N_DIM / 32, K_DIM / 32), dim3(32, 8), 0, stream>>>(w, ktb);
    k_ksq_part<<<dim3(N_DIM / 256, 16), 256, 0, stream>>>(w, kpart);
    k_ksq_fin<<<N_DIM / 256, 256, 0, stream>>>(kpart, ks, 16);
  }
  k_gemm<<<(M_DIM / 256) * (N_DIM / 128), 512, 0, stream>>>(xbf, ktb, xs, ks, bias, alpha, out);
}